// Round 20
// baseline (52.114 us; speedup 1.0000x reference)
//
#include <hip/hip_runtime.h>
#include <hip/hip_bf16.h>
#include <math.h>

// AdaptiveContrastiveLoss: x[4096][512] f32 -> scalar f32.
// R19 = R18 + T3-minimum 2-phase prefetch in gemm_fused: double-buffered
// LDS tiles; iteration t issues global_load_lds for tile t+1 into buf^1,
// computes tile t from buf, then ONE __syncthreads (implicit vmcnt drain
// after the MFMA phase has hidden the load latency). Barriers 16->9/block.
// LDS 73.9KB -> 2 blocks/CU = grid-limited residency anyway (528/256CU).
// Rest identical to R18 (42.2-42.4us, absmax 0.0).
// ws: xnb 4MB | hist 8KB | slice_top 2.1KB.

#define N 4096
#define D 512
#define NN 16777216u
#define NBF 2048         // uniform value bins over [-1,1]
#define NSLICE 528       // upper-triangle 128x128 tiles of 4096^2

typedef __attribute__((ext_vector_type(8))) short bf16x8;
typedef __attribute__((ext_vector_type(4))) float f32x4;
typedef const __attribute__((address_space(1))) void gas_t;  // global
typedef __attribute__((address_space(3))) void las_t;        // LDS

// monotone value->bin: floor((s+1)*1024), clamped to [0, NBF-1].
// bin edge at s==0 is exact, so bin >= 1024 <=> s >= 0.
__device__ __forceinline__ int val2bin(float s) {
  int b = (int)fmaf(s, 1024.0f, 1024.0f);
  return b < 0 ? 0 : (b > NBF - 1 ? NBF - 1 : b);
}
__device__ __forceinline__ unsigned short f2bf(float f) {  // RNE
  unsigned int u = __float_as_uint(f);
  u += 0x7FFFu + ((u >> 16) & 1u);
  return (unsigned short)(u >> 16);
}

// ---- 1) row norms + normalize + bf16 convert: one WAVE per row ----
__global__ __launch_bounds__(256) void norm_conv(const float* __restrict__ x,
                                                 unsigned short* __restrict__ xnb) {
  const int row = blockIdx.x * 4 + (threadIdx.x >> 6);  // 4 waves/block
  const int l = threadIdx.x & 63;
  const float4* rp = (const float4*)(x + (size_t)row * D);
  const float4 v0 = rp[l * 2];
  const float4 v1 = rp[l * 2 + 1];
  float s = v0.x * v0.x + v0.y * v0.y + v0.z * v0.z + v0.w * v0.w +
            v1.x * v1.x + v1.y * v1.y + v1.z * v1.z + v1.w * v1.w;
#pragma unroll
  for (int o = 32; o > 0; o >>= 1) s += __shfl_xor(s, o);
  const float r = 1.0f / fmaxf(sqrtf(s), 1e-8f);
  bf16x8 o8;
  o8[0] = (short)f2bf(v0.x * r); o8[1] = (short)f2bf(v0.y * r);
  o8[2] = (short)f2bf(v0.z * r); o8[3] = (short)f2bf(v0.w * r);
  o8[4] = (short)f2bf(v1.x * r); o8[5] = (short)f2bf(v1.y * r);
  o8[6] = (short)f2bf(v1.z * r); o8[7] = (short)f2bf(v1.w * r);
  *(bf16x8*)&xnb[(size_t)row * D + l * 8] = o8;
}

// ---- 2) fused GEMM + count bins, 128x128 tile, 4 waves, LDS dbuf ----
#define BM 128
#define BK 64
#define NKT (D / BK)     // 8 K-tiles
__global__ __launch_bounds__(256, 2) void gemm_fused(const unsigned short* __restrict__ xnb,
                                                     unsigned int* __restrict__ hist,
                                                     float* __restrict__ slice_top) {
  // triangular decode: linear block id -> (bx, by), bx <= by
  const int bid = blockIdx.x;
  int by = (int)((sqrtf(8.0f * (float)bid + 1.0f) - 1.0f) * 0.5f);
  while ((by + 1) * (by + 2) / 2 <= bid) ++by;
  while (by * (by + 1) / 2 > bid) --by;
  const int bx = bid - by * (by + 1) / 2;

  __shared__ unsigned short As[2][BM][BK];  // double-buffered, linear rows
  __shared__ unsigned short Bs[2][BM][BK];
  __shared__ unsigned int cnt[NBF];         // single shared histogram (R18)
  __shared__ float stop;                    // exact sum fmax(1-s,0), top bin
  const int tid = threadIdx.x;
  for (int i = tid; i < NBF; i += 256) cnt[i] = 0u;
  if (tid == 0) stop = 0.f;

  const int w = tid >> 6, l = tid & 63;
  const int wr = w >> 1, wc = w & 1;       // wave grid 2x2; wave = 64x64
  const int lr = l & 15, kgrp = l >> 4;
  const int swz = lr & 7;                  // read-side XOR swizzle
  const int bm = bx * BM, bn = by * BM;

  // staging (R11): wave w stages rows [w*32, w*32+32); LDS dest linear,
  // global source pre-swizzled: lane l -> granule (l&7)^(l>>3) of row l>>3.
  const int srow = l >> 3;
  const int gsrc = (l & 7) ^ srow;
  const unsigned short* srcA0 = xnb + (size_t)(bm + w * 32 + srow) * D + gsrc * 8;
  const unsigned short* srcB0 = xnb + (size_t)(bn + w * 32 + srow) * D + gsrc * 8;

#define STAGE(cb, kt)                                                          \
  _Pragma("unroll")                                                            \
  for (int c = 0; c < 4; ++c) {                                                \
    __builtin_amdgcn_global_load_lds((gas_t*)(srcA0 + (size_t)c * 8 * D + (kt)), \
                                     (las_t*)&As[cb][w * 32 + c * 8][0], 16, 0, 0); \
    __builtin_amdgcn_global_load_lds((gas_t*)(srcB0 + (size_t)c * 8 * D + (kt)), \
                                     (las_t*)&Bs[cb][w * 32 + c * 8][0], 16, 0, 0); \
  }

  f32x4 acc[4][4] = {};

  // prologue: stage tile 0, drain (barrier also covers cnt init)
  STAGE(0, 0)
  __syncthreads();

  int cur = 0;
#pragma unroll
  for (int t = 0; t < NKT; ++t) {
    if (t < NKT - 1) STAGE(cur ^ 1, (t + 1) * BK)  // prefetch next tile
#pragma unroll
    for (int kk = 0; kk < BK; kk += 32) {
      const int g0 = (kk >> 3) + kgrp;     // logical k-granule 0..7
      bf16x8 af[4], bf4[4];
#pragma unroll
      for (int m = 0; m < 4; ++m)
        af[m] = *(const bf16x8*)&As[cur][wr * 64 + m * 16 + lr][(g0 ^ swz) * 8];
#pragma unroll
      for (int n = 0; n < 4; ++n)
        bf4[n] = *(const bf16x8*)&Bs[cur][wc * 64 + n * 16 + lr][(g0 ^ swz) * 8];
#pragma unroll
      for (int m = 0; m < 4; ++m)
#pragma unroll
        for (int n = 0; n < 4; ++n)
          acc[m][n] = __builtin_amdgcn_mfma_f32_16x16x32_bf16(af[m], bf4[n], acc[m][n], 0, 0, 0);
    }
    __syncthreads();  // drains vmcnt (next tile staged) + all reads of cur done
    cur ^= 1;
  }

  // epilogue: count-only binning (1 LDS atomic per value)
  const unsigned int wg = (bx == by) ? 1u : 2u;
#pragma unroll
  for (int m = 0; m < 4; ++m)
#pragma unroll
    for (int n = 0; n < 4; ++n)
#pragma unroll
      for (int e = 0; e < 4; ++e) {
        const float s = acc[m][n][e];
        const int b = val2bin(s);
        atomicAdd(&cnt[b], wg);
        if (b == NBF - 1) atomicAdd(&stop, (float)wg * fmaxf(1.0f - s, 0.0f));
      }
  __syncthreads();
  // flush: integer global atomics (order-independent -> deterministic);
  // skip zero bins so only ~hot bins generate traffic.
  for (int i = tid; i < NBF; i += 256) {
    const unsigned int c = cnt[i];
    if (c) atomicAdd(&hist[i], c);
  }
  if (tid == 0) slice_top[bid] = stop;
}

// ---- 3) finalize: prefix over bins, threshold bins, midpoint range sums ----
__global__ __launch_bounds__(256) void final_loss(const unsigned int* __restrict__ hist,
                                                  const float* __restrict__ slice_top,
                                                  float* __restrict__ out,
                                                  unsigned int kneg, unsigned int kpos) {
  __shared__ unsigned int part[256], Q[256];
  __shared__ unsigned int sbp, sbn;
  __shared__ double tstage[4];
  __shared__ double dstage[2][4];
  __shared__ unsigned int ustage[2][4];
  const int tid = threadIdx.x;
  const int lane = tid & 63, wid = tid >> 6;

  // gather this thread's 8 bins
  unsigned int c8[8];
  unsigned int tot = 0;
#pragma unroll
  for (int j = 0; j < 8; ++j) {
    c8[j] = hist[tid * 8 + j];
    tot += c8[j];
  }
  // top-bin exact pos-term sum over slices
  {
    float tl = 0.f;
    for (int s = tid; s < NSLICE; s += 256) tl += slice_top[s];
    double td = tl;
#pragma unroll
    for (int o = 32; o > 0; o >>= 1) td += __shfl_xor(td, o);
    if (lane == 0) tstage[wid] = td;
  }
  // prefix scan over per-thread counts
  part[tid] = tot;
  Q[tid] = tot;
  __syncthreads();
#pragma unroll
  for (int off = 1; off < 256; off <<= 1) {
    unsigned int t2 = (tid >= off) ? Q[tid - off] : 0u;
    __syncthreads();
    Q[tid] += t2;
    __syncthreads();
  }
  const unsigned int total = Q[255];
  const unsigned int incl = Q[tid];
  const unsigned int excl = incl - part[tid];
  const unsigned int targets[2] = {kpos, kneg};
#pragma unroll
  for (int t = 0; t < 2; ++t) {
    const unsigned int r = (total == 0u) ? 0u
                         : (targets[t] < total ? targets[t] : total - 1u);
    if (total != 0u && excl <= r && r < incl) {  // exactly one owner
      unsigned int rr = r - excl, cum = 0;
      int bsel = -1;
#pragma unroll
      for (int j = 0; j < 8; ++j) {
        if (bsel < 0 && cum + c8[j] > rr) bsel = j;
        else if (bsel < 0) cum += c8[j];
      }
      if (bsel < 0) bsel = 7;
      if (t == 0) sbp = tid * 8 + (unsigned int)bsel;
      else        sbn = tid * 8 + (unsigned int)bsel;
    }
  }
  __syncthreads();
  const double topsum = tstage[0] + tstage[1] + tstage[2] + tstage[3];
  const unsigned int fbp = sbp, fbn = sbn;

  // midpoint range sums:
  //   pos: sum over bins > fbp of cnt * (1 - mid)  [top bin: exact topsum]
  //   neg: sum over bins < fbn of cnt * fmax(mid, 0)
  double psum = 0.0, nsum = 0.0;
  unsigned int pcnt = 0, ncnt = 0;
#pragma unroll
  for (int j = 0; j < 8; ++j) {
    const unsigned int b = tid * 8 + j;
    const double mid = ((double)b + 0.5) / 1024.0 - 1.0;
    if (b > fbp) {
      pcnt += c8[j];
      psum += (b == NBF - 1) ? topsum : (double)c8[j] * (1.0 - mid);
    }
    if (b < fbn) {
      ncnt += c8[j];
      if (mid > 0.0) nsum += (double)c8[j] * mid;
    }
  }
#pragma unroll
  for (int o = 32; o > 0; o >>= 1) {
    psum += __shfl_xor(psum, o);
    nsum += __shfl_xor(nsum, o);
    pcnt += __shfl_xor(pcnt, o);
    ncnt += __shfl_xor(ncnt, o);
  }
  if (lane == 0) {
    dstage[0][wid] = psum; dstage[1][wid] = nsum;
    ustage[0][wid] = pcnt; ustage[1][wid] = ncnt;
  }
  __syncthreads();
  if (tid == 0) {
    const double ps = dstage[0][0] + dstage[0][1] + dstage[0][2] + dstage[0][3];
    const double ns = dstage[1][0] + dstage[1][1] + dstage[1][2] + dstage[1][3];
    const unsigned int pc = ustage[0][0] + ustage[0][1] + ustage[0][2] + ustage[0][3];
    const unsigned int nc = ustage[1][0] + ustage[1][1] + ustage[1][2] + ustage[1][3];
    const double pl = pc ? ps / (double)pc : 0.0;
    const double nl = nc ? ns / (double)nc : 0.0;
    out[0] = (float)(pl + nl);
  }
}

extern "C" void kernel_launch(void* const* d_in, const int* in_sizes, int n_in,
                              void* d_out, int out_size, void* d_ws, size_t ws_size,
                              hipStream_t stream) {
  const float* x = (const float*)d_in[0];
  float* out = (float*)d_out;
  char* ws = (char*)d_ws;

  unsigned short* xnb = (unsigned short*)ws;                       // 4 MB
  size_t off = (size_t)N * D * 2;
  unsigned int* hist = (unsigned int*)(ws + off);                  // 8 KB
  off += (size_t)NBF * 4;
  float* slice_top = (float*)(ws + off);                           // 2.1 KB

  const unsigned int kneg = (unsigned int)ceil((double)NN * 0.2);          // 3355444
  const unsigned int kpos = (unsigned int)ceil((double)NN * (1.0 - 0.2));  // 13421773

  hipMemsetAsync(hist, 0, (size_t)NBF * 4, stream);
  norm_conv<<<N / 4, 256, 0, stream>>>(x, xnb);
  gemm_fused<<<NSLICE, 256, 0, stream>>>(xnb, hist, slice_top);
  final_loss<<<1, 256, 0, stream>>>(hist, slice_top, out, kneg, kpos);
}

// Round 21
// 37.633 us; speedup vs baseline: 1.3848x; 1.3848x over previous
//
#include <hip/hip_runtime.h>
#include <hip/hip_bf16.h>
#include <math.h>

// AdaptiveContrastiveLoss: x[4096][512] f32 -> scalar f32.
// R20 = R18 (best verified: 42.2-42.4us, absmax 0.0) + memset folded into
// norm_conv block 0 (hist zeroing; ordering via stream). R19's explicit
// LDS dbuf REGRESSED (52us: m99/m100-consistent — implicit wave overlap
// already captures it, and 74KB LDS lost the 3rd resident block).
// Ledger: epilogue copies 1/2/4/8 -> 42/42/47/52 (saturated); geometry
// 128^2/256^2/gload_lds/swizzle -> all ~30us GEMM; in-kernel finalize
// +29us (fences); dbuf +10us. 3 dispatches: norm_conv, gemm_fused,
// final_loss. ws: xnb 4MB | hist 8KB | slice_top 2.1KB.

#define N 4096
#define D 512
#define NN 16777216u
#define NBF 2048         // uniform value bins over [-1,1]
#define NSLICE 528       // upper-triangle 128x128 tiles of 4096^2

typedef __attribute__((ext_vector_type(8))) short bf16x8;
typedef __attribute__((ext_vector_type(4))) float f32x4;
typedef const __attribute__((address_space(1))) void gas_t;  // global
typedef __attribute__((address_space(3))) void las_t;        // LDS

// monotone value->bin: floor((s+1)*1024), clamped to [0, NBF-1].
// bin edge at s==0 is exact, so bin >= 1024 <=> s >= 0.
__device__ __forceinline__ int val2bin(float s) {
  int b = (int)fmaf(s, 1024.0f, 1024.0f);
  return b < 0 ? 0 : (b > NBF - 1 ? NBF - 1 : b);
}
__device__ __forceinline__ unsigned short f2bf(float f) {  // RNE
  unsigned int u = __float_as_uint(f);
  u += 0x7FFFu + ((u >> 16) & 1u);
  return (unsigned short)(u >> 16);
}

// ---- 1) row norms + normalize + bf16 convert (wave per row);
//         block 0 also zeroes hist (replaces the memset dispatch) ----
__global__ __launch_bounds__(256) void norm_conv(const float* __restrict__ x,
                                                 unsigned short* __restrict__ xnb,
                                                 unsigned int* __restrict__ hist) {
  if (blockIdx.x == 0) {
    for (int i = threadIdx.x; i < NBF; i += 256) hist[i] = 0u;
  }
  const int row = blockIdx.x * 4 + (threadIdx.x >> 6);  // 4 waves/block
  const int l = threadIdx.x & 63;
  const float4* rp = (const float4*)(x + (size_t)row * D);
  const float4 v0 = rp[l * 2];
  const float4 v1 = rp[l * 2 + 1];
  float s = v0.x * v0.x + v0.y * v0.y + v0.z * v0.z + v0.w * v0.w +
            v1.x * v1.x + v1.y * v1.y + v1.z * v1.z + v1.w * v1.w;
#pragma unroll
  for (int o = 32; o > 0; o >>= 1) s += __shfl_xor(s, o);
  const float r = 1.0f / fmaxf(sqrtf(s), 1e-8f);
  bf16x8 o8;
  o8[0] = (short)f2bf(v0.x * r); o8[1] = (short)f2bf(v0.y * r);
  o8[2] = (short)f2bf(v0.z * r); o8[3] = (short)f2bf(v0.w * r);
  o8[4] = (short)f2bf(v1.x * r); o8[5] = (short)f2bf(v1.y * r);
  o8[6] = (short)f2bf(v1.z * r); o8[7] = (short)f2bf(v1.w * r);
  *(bf16x8*)&xnb[(size_t)row * D + l * 8] = o8;
}

// ---- 2) fused GEMM + count bins, 128x128 tile, 4 waves; global-hist flush ----
#define BM 128
#define BK 64
__global__ __launch_bounds__(256, 3) void gemm_fused(const unsigned short* __restrict__ xnb,
                                                     unsigned int* __restrict__ hist,
                                                     float* __restrict__ slice_top) {
  // triangular decode: linear block id -> (bx, by), bx <= by
  const int bid = blockIdx.x;
  int by = (int)((sqrtf(8.0f * (float)bid + 1.0f) - 1.0f) * 0.5f);
  while ((by + 1) * (by + 2) / 2 <= bid) ++by;
  while (by * (by + 1) / 2 > bid) --by;
  const int bx = bid - by * (by + 1) / 2;

  __shared__ unsigned short As[BM][BK];   // linear row-major, 128B rows
  __shared__ unsigned short Bs[BM][BK];
  __shared__ unsigned int cnt[NBF];       // single shared histogram
  __shared__ float stop;                  // exact sum fmax(1-s,0), top bin
  const int tid = threadIdx.x;
  for (int i = tid; i < NBF; i += 256) cnt[i] = 0u;
  if (tid == 0) stop = 0.f;

  const int w = tid >> 6, l = tid & 63;
  const int wr = w >> 1, wc = w & 1;       // wave grid 2x2; wave = 64x64
  const int lr = l & 15, kgrp = l >> 4;
  const int swz = lr & 7;                  // read-side XOR swizzle
  const int bm = bx * BM, bn = by * BM;

  // staging (R11): wave w stages rows [w*32, w*32+32); LDS dest linear,
  // global source pre-swizzled: lane l -> granule (l&7)^(l>>3) of row l>>3.
  const int srow = l >> 3;
  const int gsrc = (l & 7) ^ srow;
  const unsigned short* srcA0 = xnb + (size_t)(bm + w * 32 + srow) * D + gsrc * 8;
  const unsigned short* srcB0 = xnb + (size_t)(bn + w * 32 + srow) * D + gsrc * 8;

  f32x4 acc[4][4] = {};

  for (int kt = 0; kt < D; kt += BK) {
    __syncthreads();  // previous iter's LDS reads done (and cnt init, iter 0)
#pragma unroll
    for (int c = 0; c < 4; ++c) {
      __builtin_amdgcn_global_load_lds((gas_t*)(srcA0 + (size_t)c * 8 * D + kt),
                                       (las_t*)&As[w * 32 + c * 8][0], 16, 0, 0);
      __builtin_amdgcn_global_load_lds((gas_t*)(srcB0 + (size_t)c * 8 * D + kt),
                                       (las_t*)&Bs[w * 32 + c * 8][0], 16, 0, 0);
    }
    __syncthreads();  // drains vmcnt: staged data visible
#pragma unroll
    for (int kk = 0; kk < BK; kk += 32) {
      const int g0 = (kk >> 3) + kgrp;     // logical k-granule 0..7
      bf16x8 af[4], bf4[4];
#pragma unroll
      for (int m = 0; m < 4; ++m)
        af[m] = *(const bf16x8*)&As[wr * 64 + m * 16 + lr][(g0 ^ swz) * 8];
#pragma unroll
      for (int n = 0; n < 4; ++n)
        bf4[n] = *(const bf16x8*)&Bs[wc * 64 + n * 16 + lr][(g0 ^ swz) * 8];
#pragma unroll
      for (int m = 0; m < 4; ++m)
#pragma unroll
        for (int n = 0; n < 4; ++n)
          acc[m][n] = __builtin_amdgcn_mfma_f32_16x16x32_bf16(af[m], bf4[n], acc[m][n], 0, 0, 0);
    }
  }

  // epilogue: count-only binning (1 LDS atomic per value)
  const unsigned int wg = (bx == by) ? 1u : 2u;
  __syncthreads();
#pragma unroll
  for (int m = 0; m < 4; ++m)
#pragma unroll
    for (int n = 0; n < 4; ++n)
#pragma unroll
      for (int e = 0; e < 4; ++e) {
        const float s = acc[m][n][e];
        const int b = val2bin(s);
        atomicAdd(&cnt[b], wg);
        if (b == NBF - 1) atomicAdd(&stop, (float)wg * fmaxf(1.0f - s, 0.0f));
      }
  __syncthreads();
  // flush: integer global atomics (order-independent -> deterministic);
  // skip zero bins so only ~hot bins generate traffic.
  for (int i = tid; i < NBF; i += 256) {
    const unsigned int c = cnt[i];
    if (c) atomicAdd(&hist[i], c);
  }
  if (tid == 0) slice_top[bid] = stop;
}

// ---- 3) finalize: prefix over bins, threshold bins, midpoint range sums ----
__global__ __launch_bounds__(256) void final_loss(const unsigned int* __restrict__ hist,
                                                  const float* __restrict__ slice_top,
                                                  float* __restrict__ out,
                                                  unsigned int kneg, unsigned int kpos) {
  __shared__ unsigned int part[256], Q[256];
  __shared__ unsigned int sbp, sbn;
  __shared__ double tstage[4];
  __shared__ double dstage[2][4];
  __shared__ unsigned int ustage[2][4];
  const int tid = threadIdx.x;
  const int lane = tid & 63, wid = tid >> 6;

  // gather this thread's 8 bins
  unsigned int c8[8];
  unsigned int tot = 0;
#pragma unroll
  for (int j = 0; j < 8; ++j) {
    c8[j] = hist[tid * 8 + j];
    tot += c8[j];
  }
  // top-bin exact pos-term sum over slices
  {
    float tl = 0.f;
    for (int s = tid; s < NSLICE; s += 256) tl += slice_top[s];
    double td = tl;
#pragma unroll
    for (int o = 32; o > 0; o >>= 1) td += __shfl_xor(td, o);
    if (lane == 0) tstage[wid] = td;
  }
  // prefix scan over per-thread counts
  part[tid] = tot;
  Q[tid] = tot;
  __syncthreads();
#pragma unroll
  for (int off = 1; off < 256; off <<= 1) {
    unsigned int t2 = (tid >= off) ? Q[tid - off] : 0u;
    __syncthreads();
    Q[tid] += t2;
    __syncthreads();
  }
  const unsigned int total = Q[255];
  const unsigned int incl = Q[tid];
  const unsigned int excl = incl - part[tid];
  const unsigned int targets[2] = {kpos, kneg};
#pragma unroll
  for (int t = 0; t < 2; ++t) {
    const unsigned int r = (total == 0u) ? 0u
                         : (targets[t] < total ? targets[t] : total - 1u);
    if (total != 0u && excl <= r && r < incl) {  // exactly one owner
      unsigned int rr = r - excl, cum = 0;
      int bsel = -1;
#pragma unroll
      for (int j = 0; j < 8; ++j) {
        if (bsel < 0 && cum + c8[j] > rr) bsel = j;
        else if (bsel < 0) cum += c8[j];
      }
      if (bsel < 0) bsel = 7;
      if (t == 0) sbp = tid * 8 + (unsigned int)bsel;
      else        sbn = tid * 8 + (unsigned int)bsel;
    }
  }
  __syncthreads();
  const double topsum = tstage[0] + tstage[1] + tstage[2] + tstage[3];
  const unsigned int fbp = sbp, fbn = sbn;

  // midpoint range sums:
  //   pos: sum over bins > fbp of cnt * (1 - mid)  [top bin: exact topsum]
  //   neg: sum over bins < fbn of cnt * fmax(mid, 0)
  double psum = 0.0, nsum = 0.0;
  unsigned int pcnt = 0, ncnt = 0;
#pragma unroll
  for (int j = 0; j < 8; ++j) {
    const unsigned int b = tid * 8 + j;
    const double mid = ((double)b + 0.5) / 1024.0 - 1.0;
    if (b > fbp) {
      pcnt += c8[j];
      psum += (b == NBF - 1) ? topsum : (double)c8[j] * (1.0 - mid);
    }
    if (b < fbn) {
      ncnt += c8[j];
      if (mid > 0.0) nsum += (double)c8[j] * mid;
    }
  }
#pragma unroll
  for (int o = 32; o > 0; o >>= 1) {
    psum += __shfl_xor(psum, o);
    nsum += __shfl_xor(nsum, o);
    pcnt += __shfl_xor(pcnt, o);
    ncnt += __shfl_xor(ncnt, o);
  }
  if (lane == 0) {
    dstage[0][wid] = psum; dstage[1][wid] = nsum;
    ustage[0][wid] = pcnt; ustage[1][wid] = ncnt;
  }
  __syncthreads();
  if (tid == 0) {
    const double ps = dstage[0][0] + dstage[0][1] + dstage[0][2] + dstage[0][3];
    const double ns = dstage[1][0] + dstage[1][1] + dstage[1][2] + dstage[1][3];
    const unsigned int pc = ustage[0][0] + ustage[0][1] + ustage[0][2] + ustage[0][3];
    const unsigned int nc = ustage[1][0] + ustage[1][1] + ustage[1][2] + ustage[1][3];
    const double pl = pc ? ps / (double)pc : 0.0;
    const double nl = nc ? ns / (double)nc : 0.0;
    out[0] = (float)(pl + nl);
  }
}

extern "C" void kernel_launch(void* const* d_in, const int* in_sizes, int n_in,
                              void* d_out, int out_size, void* d_ws, size_t ws_size,
                              hipStream_t stream) {
  const float* x = (const float*)d_in[0];
  float* out = (float*)d_out;
  char* ws = (char*)d_ws;

  unsigned short* xnb = (unsigned short*)ws;                       // 4 MB
  size_t off = (size_t)N * D * 2;
  unsigned int* hist = (unsigned int*)(ws + off);                  // 8 KB
  off += (size_t)NBF * 4;
  float* slice_top = (float*)(ws + off);                           // 2.1 KB

  const unsigned int kneg = (unsigned int)ceil((double)NN * 0.2);          // 3355444
  const unsigned int kpos = (unsigned int)ceil((double)NN * (1.0 - 0.2));  // 13421773

  norm_conv<<<N / 4, 256, 0, stream>>>(x, xnb, hist);
  gemm_fused<<<NSLICE, 256, 0, stream>>>(xnb, hist, slice_top);
  final_loss<<<1, 256, 0, stream>>>(hist, slice_top, out, kneg, kpos);
}